// Round 14
// baseline (266.681 us; speedup 1.0000x reference)
//
#include <hip/hip_runtime.h>
#include <math.h>

// DifferentiableKalmanCell: B=4096, STATE=64, OBS=32, coeffs (64,64,11), t scalar.
// R14: 32 KB LDS (5 blocks/CU target) with MINIMAL arch-register live state:
//  - P staged DIRECTLY at p0 (no pr[] across p1 -- r13's spill source).
//  - tanh scalars tv/dth (512 B) + ypart (768 B, waves 1-3) live in the R2/F
//    region during its pre-F window; p1 split: p1a compute (recurrence) ->
//    B1a -> p1b wave0 sy-reduce+residual -> B1b -> p1c F writes (scratch dead).
//  - from p2 on: identical to r13 (packed S + reg GJ + B7b K publish).
// LDS (32768 exactly):
//  R1 [0..16384):  Ph|Pl u16 swz -> T u32 -> PHt[0..8192)/Spk[8192..12288)
//                  -> K [8192..16384)
//  R2 [16384..32768): scratch{tv,dth,ypart} -> Fh|Fl u16 swz -> cov u32

typedef float f4 __attribute__((ext_vector_type(4)));
typedef float f32x4 __attribute__((ext_vector_type(4)));
typedef short b16x8 __attribute__((ext_vector_type(8)));
typedef short b16x4 __attribute__((ext_vector_type(4)));
typedef unsigned int u32;
typedef unsigned int u32x4 __attribute__((ext_vector_type(4)));
typedef unsigned short u16;

#define EPSC 1e-7f
#define MFMA(a, b, c) __builtin_amdgcn_mfma_f32_16x16x32_bf16(a, b, c, 0, 0, 0)
static constexpr size_t CU_OFF = 4096 * 64;
static constexpr size_t CD_OFF = CU_OFF + 4096ull * 4096;

__device__ __forceinline__ void split2(float x, short &h, short &l) {
  u32 u = __float_as_uint(x);
  h = (short)(u >> 16);
  float rem = x - __uint_as_float(u & 0xffff0000u);
  l = (short)(__float_as_uint(rem) >> 16);
}
__device__ __forceinline__ u32 packsplit(float x) {
  u32 u = __float_as_uint(x) & 0xffff0000u;
  float rem = x - __uint_as_float(u);
  return u | (__float_as_uint(rem) >> 16);
}
__device__ __forceinline__ float unpackf(u32 v) {
  return __uint_as_float(v & 0xffff0000u) + __uint_as_float(v << 16);
}
union U8 { u32x4 u; b16x8 s; };
__device__ __forceinline__ void unpack8(u32x4 q0, u32x4 q1, b16x8 &hi,
                                        b16x8 &lo) {
  U8 H, L;
  H.u[0] = __builtin_amdgcn_perm(q0[1], q0[0], 0x07060302u);
  H.u[1] = __builtin_amdgcn_perm(q0[3], q0[2], 0x07060302u);
  H.u[2] = __builtin_amdgcn_perm(q1[1], q1[0], 0x07060302u);
  H.u[3] = __builtin_amdgcn_perm(q1[3], q1[2], 0x07060302u);
  L.u[0] = __builtin_amdgcn_perm(q0[1], q0[0], 0x05040100u);
  L.u[1] = __builtin_amdgcn_perm(q0[3], q0[2], 0x05040100u);
  L.u[2] = __builtin_amdgcn_perm(q1[1], q1[0], 0x05040100u);
  L.u[3] = __builtin_amdgcn_perm(q1[3], q1[2], 0x05040100u);
  hi = H.s;
  lo = L.s;
}
__device__ __forceinline__ void split8v(f4 a, f4 b, b16x8 &hi, b16x8 &lo) {
#pragma unroll
  for (int j = 0; j < 4; ++j) {
    short hh, ll;
    split2(a[j], hh, ll); hi[j] = hh; lo[j] = ll;
    split2(b[j], hh, ll); hi[4 + j] = hh; lo[4 + j] = ll;
  }
}

__global__ __launch_bounds__(256, 4) void kalman_fused(
    const float *__restrict__ obs, const float *__restrict__ prev_state,
    const float *__restrict__ prev_cov, const float *__restrict__ coeffs,
    const float *__restrict__ Hm, const float *__restrict__ logQ,
    const float *__restrict__ logR, const int *__restrict__ tptr,
    float *__restrict__ out) {
  __shared__ __align__(16) unsigned char pool[32768];
  u16 *sPh = (u16 *)(pool);
  u16 *sPl = (u16 *)(pool + 8192);
  u32 *sT = (u32 *)(pool);
  u32 *sPHt = (u32 *)(pool);
  u32 *sSpk = (u32 *)(pool + 8192);
  u32 *sK = (u32 *)(pool + 8192);
  u16 *sFh = (u16 *)(pool + 16384);
  u16 *sFl = (u16 *)(pool + 24576);
  u32 *sCov = (u32 *)(pool + 16384);
  float *R2f = (float *)(pool + 16384); // tv[0..64) dth[64..128) ypart[128..320)

  const int tid = (int)threadIdx.x;
  const int b = (int)blockIdx.x;
  const int w = tid >> 6;
  const int l = tid & 63;
  const int lr = l & 15;
  const int h = l >> 4;

  // degree(t): D = degree+1 = 9 + int(1 + sin(2*pi*t/95)), D in 9..11
  const int tval = tptr[0];
  const float ang = 6.28318530717958647f * ((float)tval / 95.0f);
  const int D = 9 + (int)(1.0f + sinf(ang));

  // ---- p0: stage P direct (split+swz); tid<64: tanh-chain scalars -> R2f
  {
    const float *Pg = prev_cov + (size_t)b * 4096;
#pragma unroll
    for (int e = 0; e < 4; ++e) {
      const int idx = tid + 256 * e;
      f4 v = *(const f4 *)(Pg + 4 * idx);
      const int r = idx >> 4, c = (idx & 15) * 4;
      const int x = (r & 7) << 3;
      b16x4 h4, l4;
#pragma unroll
      for (int j = 0; j < 4; ++j) {
        short hh, ll;
        split2(v[j], hh, ll);
        h4[j] = hh; l4[j] = ll;
      }
      *(b16x4 *)(sPh + r * 64 + (c ^ x)) = h4;
      *(b16x4 *)(sPl + r * 64 + (c ^ x)) = l4;
    }
    if (tid < 64) {
      const float xx = prev_state[b * 64 + tid];
      const float tr_ = tanhf(xx);
      const float tv = fminf(fmaxf(tr_, -1.0f + EPSC), 1.0f - EPSC);
      const float sn = sqrtf(fmaxf(1.0f - tv * tv, 0.0f));
      const float mask = (tr_ > -1.0f + EPSC && tr_ < 1.0f - EPSC) ? 1.0f : 0.0f;
      R2f[tid] = tv;
      R2f[64 + tid] = -(1.0f - tr_ * tr_) * mask / sn;
    }
  }
  __syncthreads(); // B0

  // ---- p1a: yacc + Jacobian rows fr[16] via per-thread recurrence
  float yacc = 0.f;
  float fr[16];
  {
    const int o = tid & 63, g = tid >> 6;
#pragma unroll
    for (int ii = 0; ii < 16; ++ii) {
      const int i = g * 16 + ii;
      const float tv = R2f[i], dth = R2f[64 + i];
      const float sn = sqrtf(fmaxf(1.0f - tv * tv, 0.0f));
      const float *cp = coeffs + (size_t)(i * 64 + o) * 11;
      f4 q0 = *(const f4 *)(cp);
      f4 q1 = *(const f4 *)(cp + 4);
      f4 q2 = *(const f4 *)(cp + 7); // q2[1..3] = cp[8..10]
      float cy[11];
#pragma unroll
      for (int j = 0; j < 4; ++j) { cy[j] = q0[j]; cy[4 + j] = q1[j]; }
      cy[8] = q2[1]; cy[9] = q2[2]; cy[10] = q2[3];
      if (D < 10) cy[9] = 0.f;
      if (D < 11) cy[10] = 0.f;
      float yac = fmaf(cy[1], tv, cy[0]);
      float wac = cy[1] * sn;
      float cm2 = 1.f, cm1 = tv, sm2 = 0.f, sm1 = sn;
      const float tv2 = 2.f * tv;
#pragma unroll
      for (int d = 2; d <= 10; ++d) {
        const float cc = fmaf(tv2, cm1, -cm2);
        const float ss = fmaf(tv2, sm1, -sm2);
        yac = fmaf(cy[d], cc, yac);
        wac = fmaf(cy[d] * (float)d, ss, wac);
        cm2 = cm1; cm1 = cc; sm2 = sm1; sm1 = ss;
      }
      yacc += yac;
      fr[ii] = -dth * wac;
    }
    if (w > 0) R2f[128 + (w - 1) * 64 + o] = yacc; // ypart (waves 1-3)
  }
  __syncthreads(); // B1a: tv/dth reads + ypart writes done

  // ---- p1b: wave0 totals sy (own partial in reg) + residual (all 64 lanes
  //      active -- ds_bpermute needs source-lane exec on)
  float syl = 0.f, residreg = 0.f;
  if (w == 0) {
    syl = yacc + R2f[128 + l] + R2f[192 + l] + R2f[256 + l];
    const int r = l & 31;
    float racc = obs[b * 32 + r];
    const float *Hr = Hm + r * 64;
#pragma unroll
    for (int c = 0; c < 64; c += 4) {
      f4 hv = *(const f4 *)(Hr + c);
#pragma unroll
      for (int j = 0; j < 4; ++j)
        racc = fmaf(-hv[j], __shfl(syl, c + j, 64), racc);
    }
    residreg = racc; // rows 0..31 valid in lanes 0..31
  }
  __syncthreads(); // B1b: ypart reads done; scratch dead

  // ---- p1c: write F (split, swz) over the dead scratch region
  {
    const int o = tid & 63, g = tid >> 6;
    b16x8 fh0, fh1, fl0, fl1;
#pragma unroll
    for (int j = 0; j < 8; ++j) {
      short hh, ll;
      split2(fr[j], hh, ll); fh0[j] = hh; fl0[j] = ll;
      split2(fr[8 + j], hh, ll); fh1[j] = hh; fl1[j] = ll;
    }
    const int x = (o & 7) << 3;
    *(b16x8 *)(sFh + o * 64 + ((g * 16) ^ x)) = fh0;
    *(b16x8 *)(sFh + o * 64 + ((g * 16 + 8) ^ x)) = fh1;
    *(b16x8 *)(sFl + o * 64 + ((g * 16) ^ x)) = fl0;
    *(b16x8 *)(sFl + o * 64 + ((g * 16 + 8) ^ x)) = fl1;
  }
  __syncthreads(); // B2: F published

  // ---- p2 (MFMA): T = F * P (P symmetric -> B-frag = row read)
  f32x4 accT[4] = {{0.f, 0.f, 0.f, 0.f}, {0.f, 0.f, 0.f, 0.f},
                   {0.f, 0.f, 0.f, 0.f}, {0.f, 0.f, 0.f, 0.f}};
  {
    const int m = 16 * w + lr;
    const int xA = (m & 7) << 3;
#pragma unroll
    for (int kc = 0; kc < 2; ++kc) {
      const int k = kc * 32 + h * 8;
      b16x8 Ah = *(const b16x8 *)(sFh + m * 64 + (k ^ xA));
      b16x8 Al = *(const b16x8 *)(sFl + m * 64 + (k ^ xA));
#pragma unroll
      for (int t = 0; t < 4; ++t) {
        const int n = t * 16 + lr;
        const int xB = (n & 7) << 3;
        b16x8 Bh = *(const b16x8 *)(sPh + n * 64 + (k ^ xB));
        b16x8 Bl = *(const b16x8 *)(sPl + n * 64 + (k ^ xB));
        accT[t] = MFMA(Ah, Bh, accT[t]);
        accT[t] = MFMA(Al, Bh, accT[t]);
        accT[t] = MFMA(Ah, Bl, accT[t]);
      }
    }
  }
  __syncthreads(); // B3: P reads drained; overwrite with packed T
  {
    const int r0 = 16 * w + h * 4;
#pragma unroll
    for (int t = 0; t < 4; ++t)
#pragma unroll
      for (int j = 0; j < 4; ++j) {
        const int rr = r0 + j, cc = t * 16 + lr;
        sT[rr * 64 + (cc ^ ((rr & 7) << 2))] = packsplit(accT[t][j]);
      }
  }

  // ---- p3 (MFMA): cov = T * F^T + diag(q). A = T band-local.
  f32x4 accC[4] = {{0.f, 0.f, 0.f, 0.f}, {0.f, 0.f, 0.f, 0.f},
                   {0.f, 0.f, 0.f, 0.f}, {0.f, 0.f, 0.f, 0.f}};
  {
    const int m = 16 * w + lr;
    const int xA = (m & 7) << 2;
    const u32 *Tb = sT + m * 64;
#pragma unroll
    for (int kc = 0; kc < 2; ++kc) {
      const int k = kc * 32 + h * 8;
      u32x4 q0 = *(const u32x4 *)(Tb + (k ^ xA));
      u32x4 q1 = *(const u32x4 *)(Tb + ((k + 4) ^ xA));
      b16x8 Ah, Al;
      unpack8(q0, q1, Ah, Al);
#pragma unroll
      for (int t = 0; t < 4; ++t) {
        const int n = t * 16 + lr;
        const int xB = (n & 7) << 3;
        b16x8 Bh = *(const b16x8 *)(sFh + n * 64 + (k ^ xB));
        b16x8 Bl = *(const b16x8 *)(sFl + n * 64 + (k ^ xB));
        accC[t] = MFMA(Ah, Bh, accC[t]);
        accC[t] = MFMA(Al, Bh, accC[t]);
        accC[t] = MFMA(Ah, Bl, accC[t]);
      }
    }
  }
  __syncthreads(); // B4: F and T reads drained
  {
    const int r0 = 16 * w + h * 4;
    f4 lq = *(const f4 *)(logQ + r0);
    float qv[4];
#pragma unroll
    for (int j = 0; j < 4; ++j) qv[j] = expf(lq[j]);
#pragma unroll
    for (int t = 0; t < 4; ++t)
#pragma unroll
      for (int j = 0; j < 4; ++j) {
        const int rr = r0 + j, cc = t * 16 + lr;
        float v = accC[t][j];
        if (rr == cc) v += qv[j];
        sCov[rr * 64 + (cc ^ ((rr & 7) << 2))] = packsplit(v);
      }
  }

  // ---- p4 (MFMA): PHt = cov * H^T (A = cov band-local; B = H global split)
  {
    f32x4 acc[2] = {{0.f, 0.f, 0.f, 0.f}, {0.f, 0.f, 0.f, 0.f}};
    const int m = 16 * w + lr;
    const int xA = (m & 7) << 2;
    const u32 *Cb = sCov + m * 64;
#pragma unroll
    for (int kc = 0; kc < 2; ++kc) {
      const int k = kc * 32 + h * 8;
      u32x4 q0 = *(const u32x4 *)(Cb + (k ^ xA));
      u32x4 q1 = *(const u32x4 *)(Cb + ((k + 4) ^ xA));
      b16x8 Ah, Al;
      unpack8(q0, q1, Ah, Al);
#pragma unroll
      for (int t = 0; t < 2; ++t) {
        const int n = t * 16 + lr;
        const float *Hr = Hm + n * 64 + k;
        f4 b0 = *(const f4 *)(Hr);
        f4 b1 = *(const f4 *)(Hr + 4);
        b16x8 Bh, Bl;
        split8v(b0, b1, Bh, Bl);
        acc[t] = MFMA(Ah, Bh, acc[t]);
        acc[t] = MFMA(Al, Bh, acc[t]);
        acc[t] = MFMA(Ah, Bl, acc[t]);
      }
    }
    const int r0 = 16 * w + h * 4;
#pragma unroll
    for (int t = 0; t < 2; ++t)
#pragma unroll
      for (int j = 0; j < 4; ++j) {
        const int rr = r0 + j, cc = t * 16 + lr;
        sPHt[rr * 32 + (cc ^ ((rr & 7) << 2))] = packsplit(acc[t][j]);
      }
  }
  __syncthreads(); // B5: PHt published

  // ---- p5 (MFMA): S = H * PHt + diag(r) -> packed swz @ [8192..12288)
  {
    const int tr = w >> 1, tc = w & 1;
    f32x4 acc = {0.f, 0.f, 0.f, 0.f};
    const int m = tr * 16 + lr;
    const int n = tc * 16 + lr;
#pragma unroll
    for (int kc = 0; kc < 2; ++kc) {
      const int k = kc * 32 + h * 8;
      const float *Hr = Hm + m * 64 + k;
      f4 a0 = *(const f4 *)(Hr);
      f4 a1 = *(const f4 *)(Hr + 4);
      b16x8 Ah, Al;
      split8v(a0, a1, Ah, Al);
      u32x4 q0, q1;
#pragma unroll
      for (int j = 0; j < 4; ++j)
        q0[j] = sPHt[(k + j) * 32 + (n ^ (j << 2))];
#pragma unroll
      for (int j = 0; j < 4; ++j)
        q1[j] = sPHt[(k + 4 + j) * 32 + (n ^ ((4 + j) << 2))];
      b16x8 Bh, Bl;
      unpack8(q0, q1, Bh, Bl);
      acc = MFMA(Ah, Bh, acc);
      acc = MFMA(Al, Bh, acc);
      acc = MFMA(Ah, Bl, acc);
    }
    const int r0s = tr * 16 + h * 4;
    f4 lrv = *(const f4 *)(logR + r0s);
#pragma unroll
    for (int j = 0; j < 4; ++j) {
      const int rr = r0s + j, cc = tc * 16 + lr;
      float v = acc[j];
      if (rr == cc) v += expf(lrv[j]);
      sSpk[rr * 32 + (cc ^ ((rr & 7) << 2))] = packsplit(v);
    }
  }
  __syncthreads(); // B6: S published

  // ---- p6: S^-1 in-register Gauss-Jordan on wave 0 (packed I/O, in place)
  if (w == 0) {
    const int mr = l >> 1, half = l & 1;
    const int xm = (mr & 7) << 2;
    float s0[16];
#pragma unroll
    for (int qi = 0; qi < 4; ++qi) {
      u32x4 qv = *(const u32x4 *)(sSpk + mr * 32 + ((half * 16 + qi * 4) ^ xm));
#pragma unroll
      for (int j = 0; j < 4; ++j) s0[qi * 4 + j] = unpackf(qv[j]);
    }
#pragma unroll
    for (int p = 0; p < 32; ++p) {
      const int ph = p >> 4, pi = p & 15;
      float prow[16];
#pragma unroll
      for (int j = 0; j < 16; ++j) prow[j] = __shfl(s0[j], 2 * p + half, 64);
      const float dpp = __shfl(s0[pi], 2 * p + ph, 64);
      const float d = 1.0f / dpp;
      const float fv = __shfl(s0[pi], (l & 62) + ph, 64);
      if (mr == p) {
#pragma unroll
        for (int j = 0; j < 16; ++j) s0[j] = prow[j] * d;
        if (half == ph) s0[pi] = d;
      } else {
        const float fd = fv * d;
#pragma unroll
        for (int j = 0; j < 16; ++j) s0[j] = fmaf(-fd, prow[j], s0[j]);
        if (half == ph) s0[pi] = -fd;
      }
    }
#pragma unroll
    for (int qi = 0; qi < 4; ++qi) {
      u32x4 ov;
#pragma unroll
      for (int j = 0; j < 4; ++j) ov[j] = packsplit(s0[qi * 4 + j]);
      *(u32x4 *)(sSpk + mr * 32 + ((half * 16 + qi * 4) ^ xm)) = ov;
    }
  }
  __syncthreads(); // B7: S^-1 published

  // ---- p7 (MFMA): K = PHt * S^-1 (B row-read via symmetry); accs in regs
  //      across B7b, then K overwrites the S^-1 region.
  f32x4 accK[2] = {{0.f, 0.f, 0.f, 0.f}, {0.f, 0.f, 0.f, 0.f}};
  {
    const int m = 16 * w + lr;
    const int xA = (m & 7) << 2;
    const int k = h * 8;
    u32x4 q0 = *(const u32x4 *)(sPHt + m * 32 + (k ^ xA));
    u32x4 q1 = *(const u32x4 *)(sPHt + m * 32 + ((k + 4) ^ xA));
    b16x8 Ah, Al;
    unpack8(q0, q1, Ah, Al);
#pragma unroll
    for (int t = 0; t < 2; ++t) {
      const int n = t * 16 + lr;
      const int xB = (n & 7) << 2;
      u32x4 b0 = *(const u32x4 *)(sSpk + n * 32 + (k ^ xB));
      u32x4 b1 = *(const u32x4 *)(sSpk + n * 32 + ((k + 4) ^ xB));
      b16x8 Bh, Bl;
      unpack8(b0, b1, Bh, Bl);
      accK[t] = MFMA(Ah, Bh, accK[t]);
      accK[t] = MFMA(Al, Bh, accK[t]);
      accK[t] = MFMA(Ah, Bl, accK[t]);
    }
  }
  __syncthreads(); // B7b: S^-1 reads drained
  {
    const int r0 = 16 * w + h * 4;
#pragma unroll
    for (int t = 0; t < 2; ++t)
#pragma unroll
      for (int j = 0; j < 4; ++j) {
        const int rr = r0 + j, cc = t * 16 + lr;
        sK[rr * 32 + (cc ^ ((rr & 7) << 2))] = packsplit(accK[t][j]);
      }
  }
  __syncthreads(); // B8: K published

  // ---- p8: state_update (wave 0, sy/resid in regs) + cov_update
  if (tid < 64) {
    float su = syl;
    const int x = (l & 7) << 2;
    const u32 *Kb = sK + l * 32;
#pragma unroll
    for (int c0 = 0; c0 < 32; c0 += 4) {
      u32x4 q = *(const u32x4 *)(Kb + (c0 ^ x));
#pragma unroll
      for (int j = 0; j < 4; ++j)
        su = fmaf(unpackf(q[j]), __shfl(residreg, c0 + j, 64), su);
    }
    out[b * 64 + l] = su;
  }
  {
    const int m = 16 * w + lr;
    const int xA = (m & 7) << 2;
    const int k = h * 8;
    u32x4 q0 = *(const u32x4 *)(sK + m * 32 + (k ^ xA));
    u32x4 q1 = *(const u32x4 *)(sK + m * 32 + ((k + 4) ^ xA));
#pragma unroll
    for (int j = 0; j < 4; ++j) { // negate both halves: -K
      q0[j] ^= 0x80008000u;
      q1[j] ^= 0x80008000u;
    }
    b16x8 Ah, Al;
    unpack8(q0, q1, Ah, Al);
    const int r0 = 16 * w + h * 4;
    float *outc = out + CU_OFF + (size_t)b * 4096;
#pragma unroll
    for (int t = 0; t < 4; ++t) {
      const int n = t * 16 + lr;
      const int xB = (n & 7) << 2;
      u32x4 p0 = *(const u32x4 *)(sPHt + n * 32 + (k ^ xB));
      u32x4 p1 = *(const u32x4 *)(sPHt + n * 32 + ((k + 4) ^ xB));
      b16x8 Bh, Bl;
      unpack8(p0, p1, Bh, Bl);
      f32x4 acc;
#pragma unroll
      for (int j = 0; j < 4; ++j) {
        const int rr = r0 + j;
        acc[j] = unpackf(sCov[rr * 64 + (n ^ ((rr & 7) << 2))]);
      }
      acc = MFMA(Ah, Bh, acc);
      acc = MFMA(Al, Bh, acc);
      acc = MFMA(Ah, Bl, acc);
#pragma unroll
      for (int j = 0; j < 4; ++j) {
        const int rr = r0 + j;
        outc[rr * 64 + n] = acc[j];
        if (rr == n) out[CD_OFF + b * 64 + rr] = acc[j];
      }
    }
  }
}

extern "C" void kernel_launch(void *const *d_in, const int *in_sizes, int n_in,
                              void *d_out, int out_size, void *d_ws,
                              size_t ws_size, hipStream_t stream) {
  const float *obs = (const float *)d_in[0];
  const float *prev_state = (const float *)d_in[1];
  const float *prev_cov = (const float *)d_in[2];
  const float *coeffs = (const float *)d_in[3];
  const float *Hm = (const float *)d_in[4];
  const float *logQ = (const float *)d_in[5];
  const float *logR = (const float *)d_in[6];
  const int *tptr = (const int *)d_in[7];
  (void)in_sizes; (void)n_in; (void)out_size; (void)d_ws; (void)ws_size;
  kalman_fused<<<dim3(4096), dim3(256), 0, stream>>>(
      obs, prev_state, prev_cov, coeffs, Hm, logQ, logR, tptr, (float *)d_out);
}

// Round 15
// 115.661 us; speedup vs baseline: 2.3057x; 2.3057x over previous
//
#include <hip/hip_runtime.h>
#include <math.h>

// DifferentiableKalmanCell: B=4096, STATE=64, OBS=32, coeffs (64,64,11), t scalar.
// One block per batch; MFMA (bf16 split hi/lo) for all GEMM phases; Chebyshev by
// recurrence; S^-1 by single-wave register Gauss-Jordan.
// R15 = restore R7 (best verified: 115.85 us bench / ~134 us rocprof).
// Occupancy ladder closed: 5-block variants (r11-r14) all spill (kernel needs
// ~128 total regs; 5 blocks allows ~102); 32-wave (r9) clamps to 32 VGPR; ILP
// 2-batch (r10) halves blocks. Work-reduction closed: r8 cut VALU 43->37%, dur
// unchanged (stall-bound). 4 blocks/CU @ 38144 B LDS is the operating point.
//   - P/F splits: u16[64][64] XOR-swizzled (chunk ^ (row&7)), no pad.
//   - T, cov_pred: packed u32 (hi16|lo16) [64][64] swizzled; PHt, K: [64][32].
//     Packing is bit-identical to split-on-read (split moved to write time).
//   Layout: @0 Ph|Pl -> T -> PHt|K (16384) | @16384 Fh|Fl -> cov (16384)
//           @32768 S[32][36] f32 (ypart/tanh-scalar overlay pre-p5) (4608)
//           @37376 sy,sresid,sq,sr (768)  => total 38144.

typedef float f4 __attribute__((ext_vector_type(4)));
typedef float f32x4 __attribute__((ext_vector_type(4)));
typedef short b16x8 __attribute__((ext_vector_type(8)));
typedef short b16x4 __attribute__((ext_vector_type(4)));
typedef unsigned int u32;
typedef unsigned int u32x4 __attribute__((ext_vector_type(4)));
typedef unsigned short u16;

#define EPSC 1e-7f
#define MFMA(a, b, c) __builtin_amdgcn_mfma_f32_16x16x32_bf16(a, b, c, 0, 0, 0)
static constexpr size_t CU_OFF = 4096 * 64;
static constexpr size_t CD_OFF = CU_OFF + 4096ull * 4096;

__device__ __forceinline__ void split2(float x, short &h, short &l) {
  u32 u = __float_as_uint(x);
  h = (short)(u >> 16);
  float rem = x - __uint_as_float(u & 0xffff0000u);
  l = (short)(__float_as_uint(rem) >> 16);
}
__device__ __forceinline__ u32 packsplit(float x) {
  u32 u = __float_as_uint(x) & 0xffff0000u;
  float rem = x - __uint_as_float(u);
  return u | (__float_as_uint(rem) >> 16);
}
__device__ __forceinline__ float unpackf(u32 v) {
  return __uint_as_float(v & 0xffff0000u) + __uint_as_float(v << 16);
}
union U8 { u32x4 u; b16x8 s; };
__device__ __forceinline__ void unpack8(u32x4 q0, u32x4 q1, b16x8 &hi,
                                        b16x8 &lo) {
  U8 H, L;
  H.u[0] = __builtin_amdgcn_perm(q0[1], q0[0], 0x07060302u);
  H.u[1] = __builtin_amdgcn_perm(q0[3], q0[2], 0x07060302u);
  H.u[2] = __builtin_amdgcn_perm(q1[1], q1[0], 0x07060302u);
  H.u[3] = __builtin_amdgcn_perm(q1[3], q1[2], 0x07060302u);
  L.u[0] = __builtin_amdgcn_perm(q0[1], q0[0], 0x05040100u);
  L.u[1] = __builtin_amdgcn_perm(q0[3], q0[2], 0x05040100u);
  L.u[2] = __builtin_amdgcn_perm(q1[1], q1[0], 0x05040100u);
  L.u[3] = __builtin_amdgcn_perm(q1[3], q1[2], 0x05040100u);
  hi = H.s;
  lo = L.s;
}
__device__ __forceinline__ void split8v(f4 a, f4 b, b16x8 &hi, b16x8 &lo) {
#pragma unroll
  for (int j = 0; j < 4; ++j) {
    short hh, ll;
    split2(a[j], hh, ll); hi[j] = hh; lo[j] = ll;
    split2(b[j], hh, ll); hi[4 + j] = hh; lo[4 + j] = ll;
  }
}

__global__ __launch_bounds__(256, 4) void kalman_fused(
    const float *__restrict__ obs, const float *__restrict__ prev_state,
    const float *__restrict__ prev_cov, const float *__restrict__ coeffs,
    const float *__restrict__ Hm, const float *__restrict__ logQ,
    const float *__restrict__ logR, const int *__restrict__ tptr,
    float *__restrict__ out) {
  __shared__ __align__(16) unsigned char pool[38144];
  u16 *sPh = (u16 *)(pool);            // [64][64] swz
  u16 *sPl = (u16 *)(pool + 8192);
  u32 *sT = (u32 *)(pool);             // packed [64][64] swz, over P
  u32 *sPHt = (u32 *)(pool);           // packed [64][32] swz, over T rows 0..31
  u32 *sK = (u32 *)(pool + 8192);      // packed [64][32] swz, over T rows 32..63
  u16 *sFh = (u16 *)(pool + 16384);    // [64][64] swz
  u16 *sFl = (u16 *)(pool + 24576);
  u32 *sCov = (u32 *)(pool + 16384);   // packed [64][64] swz, over F
  float *sS = (float *)(pool + 32768); // f32 [32][36]
  float *ypart = (float *)(pool + 32768); // overlay (dead before p5)
  float *sTv = (float *)(pool + 33792);
  float *sSn = (float *)(pool + 34048);
  float *sDth = (float *)(pool + 34304);
  float *sy = (float *)(pool + 37376);
  float *sresid = (float *)(pool + 37632);
  float *sq = (float *)(pool + 37760);
  float *sr = (float *)(pool + 38016);

  const int tid = (int)threadIdx.x;
  const int b = (int)blockIdx.x;
  const int w = tid >> 6;
  const int l = tid & 63;
  const int lr = l & 15;
  const int h = l >> 4;

  // degree(t): D = degree+1 = 9 + int(1 + sin(2*pi*t/95)), D in 9..11
  const int tval = tptr[0];
  const float ang = 6.28318530717958647f * ((float)tval / 95.0f);
  const int D = 9 + (int)(1.0f + sinf(ang));

  // ---- p0: stage P (bf16 hi/lo split, swizzled), q/r, tanh-chain scalars
  {
    const float *Pg = prev_cov + (size_t)b * 4096;
#pragma unroll
    for (int e = 0; e < 4; ++e) {
      const int idx = tid + 256 * e;
      f4 v = *(const f4 *)(Pg + 4 * idx);
      const int r = idx >> 4, c = (idx & 15) * 4;
      const int x = (r & 7) << 3;
      b16x4 h4, l4;
#pragma unroll
      for (int j = 0; j < 4; ++j) {
        short hh, ll;
        split2(v[j], hh, ll);
        h4[j] = hh; l4[j] = ll;
      }
      *(b16x4 *)(sPh + r * 64 + (c ^ x)) = h4;
      *(b16x4 *)(sPl + r * 64 + (c ^ x)) = l4;
    }
    if (tid < 64) {
      sq[tid] = expf(logQ[tid]);
      const float xx = prev_state[b * 64 + tid];
      const float tr_ = tanhf(xx);
      const float tv = fminf(fmaxf(tr_, -1.0f + EPSC), 1.0f - EPSC);
      const float sn = sqrtf(fmaxf(1.0f - tv * tv, 0.0f));
      const float mask = (tr_ > -1.0f + EPSC && tr_ < 1.0f - EPSC) ? 1.0f : 0.0f;
      sTv[tid] = tv;
      sSn[tid] = sn;
      sDth[tid] = -(1.0f - tr_ * tr_) * mask / sn;
    } else if (tid < 96) {
      sr[tid - 64] = expf(logR[tid - 64]);
    }
  }
  __syncthreads(); // B0

  // ---- p1: y partials + Jacobian F (Chebyshev recurrence), F -> split swz
  {
    const int o = tid & 63, g = tid >> 6;
    float yacc = 0.f;
    float fr[16];
#pragma unroll
    for (int ii = 0; ii < 16; ++ii) {
      const int i = g * 16 + ii;
      const float tv = sTv[i], sn = sSn[i], dth = sDth[i];
      const float *cp = coeffs + (size_t)(i * 64 + o) * 11;
      f4 q0 = *(const f4 *)(cp);
      f4 q1 = *(const f4 *)(cp + 4);
      f4 q2 = *(const f4 *)(cp + 7); // elements 7..10 (in-bounds at tail)
      float cy[11];
#pragma unroll
      for (int j = 0; j < 4; ++j) { cy[j] = q0[j]; cy[4 + j] = q1[j]; }
      cy[8] = q2[1]; cy[9] = q2[2]; cy[10] = q2[3];
      if (D < 10) cy[9] = 0.f;
      if (D < 11) cy[10] = 0.f;
      float yac = fmaf(cy[1], tv, cy[0]);
      float wac = cy[1] * sn;
      float cm2 = 1.f, cm1 = tv, sm2 = 0.f, sm1 = sn;
      const float tv2 = 2.f * tv;
#pragma unroll
      for (int d = 2; d <= 10; ++d) {
        const float cc = fmaf(tv2, cm1, -cm2);
        const float ss = fmaf(tv2, sm1, -sm2);
        yac = fmaf(cy[d], cc, yac);
        wac = fmaf(cy[d] * (float)d, ss, wac);
        cm2 = cm1; cm1 = cc; sm2 = sm1; sm1 = ss;
      }
      yacc += yac;
      fr[ii] = -dth * wac;
    }
    b16x8 fh0, fh1, fl0, fl1;
#pragma unroll
    for (int j = 0; j < 8; ++j) {
      short hh, ll;
      split2(fr[j], hh, ll); fh0[j] = hh; fl0[j] = ll;
      split2(fr[8 + j], hh, ll); fh1[j] = hh; fl1[j] = ll;
    }
    const int x = (o & 7) << 3;
    *(b16x8 *)(sFh + o * 64 + ((g * 16) ^ x)) = fh0;
    *(b16x8 *)(sFh + o * 64 + ((g * 16 + 8) ^ x)) = fh1;
    *(b16x8 *)(sFl + o * 64 + ((g * 16) ^ x)) = fl0;
    *(b16x8 *)(sFl + o * 64 + ((g * 16 + 8) ^ x)) = fl1;
    ypart[g * 64 + o] = yacc;
  }
  __syncthreads(); // B1
  if (tid < 64)
    sy[tid] = ypart[tid] + ypart[64 + tid] + ypart[128 + tid] + ypart[192 + tid];
  __syncthreads(); // B2

  // residual (tid<32; others proceed to p2)
  if (tid < 32) {
    float racc = obs[b * 32 + tid];
    const float *Hr = Hm + tid * 64;
#pragma unroll
    for (int s = 0; s < 64; s += 4) {
      f4 hv = *(const f4 *)(Hr + s);
      racc -= hv[0] * sy[s] + hv[1] * sy[s + 1] + hv[2] * sy[s + 2] +
              hv[3] * sy[s + 3];
    }
    sresid[tid] = racc;
  }

  // ---- p2 (MFMA): T = F * P (P symmetric -> B-frag = row read)
  f32x4 accT[4] = {{0.f, 0.f, 0.f, 0.f}, {0.f, 0.f, 0.f, 0.f},
                   {0.f, 0.f, 0.f, 0.f}, {0.f, 0.f, 0.f, 0.f}};
  {
    const int m = 16 * w + lr;
    const int xA = (m & 7) << 3;
#pragma unroll
    for (int kc = 0; kc < 2; ++kc) {
      const int k = kc * 32 + h * 8;
      b16x8 Ah = *(const b16x8 *)(sFh + m * 64 + (k ^ xA));
      b16x8 Al = *(const b16x8 *)(sFl + m * 64 + (k ^ xA));
#pragma unroll
      for (int t = 0; t < 4; ++t) {
        const int n = t * 16 + lr;
        const int xB = (n & 7) << 3;
        b16x8 Bh = *(const b16x8 *)(sPh + n * 64 + (k ^ xB));
        b16x8 Bl = *(const b16x8 *)(sPl + n * 64 + (k ^ xB));
        accT[t] = MFMA(Ah, Bh, accT[t]);
        accT[t] = MFMA(Al, Bh, accT[t]);
        accT[t] = MFMA(Ah, Bl, accT[t]);
      }
    }
  }
  __syncthreads(); // B3: P reads drained; overwrite with packed T
  {
    const int r0 = 16 * w + h * 4;
#pragma unroll
    for (int t = 0; t < 4; ++t)
#pragma unroll
      for (int j = 0; j < 4; ++j) {
        const int rr = r0 + j, cc = t * 16 + lr;
        sT[rr * 64 + (cc ^ ((rr & 7) << 2))] = packsplit(accT[t][j]);
      }
  }

  // ---- p3 (MFMA): cov_pred = T * F^T + diag(q). A = T band-local.
  f32x4 accC[4] = {{0.f, 0.f, 0.f, 0.f}, {0.f, 0.f, 0.f, 0.f},
                   {0.f, 0.f, 0.f, 0.f}, {0.f, 0.f, 0.f, 0.f}};
  {
    const int m = 16 * w + lr;
    const int xA = (m & 7) << 2;
    const u32 *Tb = sT + m * 64;
#pragma unroll
    for (int kc = 0; kc < 2; ++kc) {
      const int k = kc * 32 + h * 8;
      u32x4 q0 = *(const u32x4 *)(Tb + (k ^ xA));
      u32x4 q1 = *(const u32x4 *)(Tb + ((k + 4) ^ xA));
      b16x8 Ah, Al;
      unpack8(q0, q1, Ah, Al);
#pragma unroll
      for (int t = 0; t < 4; ++t) {
        const int n = t * 16 + lr;
        const int xB = (n & 7) << 3;
        b16x8 Bh = *(const b16x8 *)(sFh + n * 64 + (k ^ xB));
        b16x8 Bl = *(const b16x8 *)(sFl + n * 64 + (k ^ xB));
        accC[t] = MFMA(Ah, Bh, accC[t]);
        accC[t] = MFMA(Al, Bh, accC[t]);
        accC[t] = MFMA(Ah, Bl, accC[t]);
      }
    }
  }
  __syncthreads(); // B4: F and T reads drained; overwrite F with packed cov
  {
    const int r0 = 16 * w + h * 4;
#pragma unroll
    for (int t = 0; t < 4; ++t)
#pragma unroll
      for (int j = 0; j < 4; ++j) {
        const int rr = r0 + j, cc = t * 16 + lr;
        float v = accC[t][j];
        if (rr == cc) v += sq[rr];
        sCov[rr * 64 + (cc ^ ((rr & 7) << 2))] = packsplit(v);
      }
  }

  // ---- p4 (MFMA): PHt = cov_pred * H^T (A = cov band-local; B = H global).
  //      Writes packed sPHt over dead T rows 0..31.
  {
    f32x4 acc[2] = {{0.f, 0.f, 0.f, 0.f}, {0.f, 0.f, 0.f, 0.f}};
    const int m = 16 * w + lr;
    const int xA = (m & 7) << 2;
    const u32 *Cb = sCov + m * 64;
#pragma unroll
    for (int kc = 0; kc < 2; ++kc) {
      const int k = kc * 32 + h * 8;
      u32x4 q0 = *(const u32x4 *)(Cb + (k ^ xA));
      u32x4 q1 = *(const u32x4 *)(Cb + ((k + 4) ^ xA));
      b16x8 Ah, Al;
      unpack8(q0, q1, Ah, Al);
#pragma unroll
      for (int t = 0; t < 2; ++t) {
        const int n = t * 16 + lr;
        const float *Hr = Hm + n * 64 + k;
        f4 b0 = *(const f4 *)(Hr);
        f4 b1 = *(const f4 *)(Hr + 4);
        b16x8 Bh, Bl;
        split8v(b0, b1, Bh, Bl);
        acc[t] = MFMA(Ah, Bh, acc[t]);
        acc[t] = MFMA(Al, Bh, acc[t]);
        acc[t] = MFMA(Ah, Bl, acc[t]);
      }
    }
    const int r0 = 16 * w + h * 4;
#pragma unroll
    for (int t = 0; t < 2; ++t)
#pragma unroll
      for (int j = 0; j < 4; ++j) {
        const int rr = r0 + j, cc = t * 16 + lr;
        sPHt[rr * 32 + (cc ^ ((rr & 7) << 2))] = packsplit(acc[t][j]);
      }
  }
  __syncthreads(); // B5

  // ---- p5 (MFMA): S = H * PHt + diag(r); wave w -> tile (w>>1, w&1)
  {
    const int tr = w >> 1, tc = w & 1;
    f32x4 acc = {0.f, 0.f, 0.f, 0.f};
    const int m = tr * 16 + lr;
    const int n = tc * 16 + lr;
#pragma unroll
    for (int kc = 0; kc < 2; ++kc) {
      const int k = kc * 32 + h * 8;
      const float *Hr = Hm + m * 64 + k;
      f4 a0 = *(const f4 *)(Hr);
      f4 a1 = *(const f4 *)(Hr + 4);
      b16x8 Ah, Al;
      split8v(a0, a1, Ah, Al);
      u32x4 q0, q1;
#pragma unroll
      for (int j = 0; j < 4; ++j)
        q0[j] = sPHt[(k + j) * 32 + (n ^ (j << 2))];
#pragma unroll
      for (int j = 0; j < 4; ++j)
        q1[j] = sPHt[(k + 4 + j) * 32 + (n ^ ((4 + j) << 2))];
      b16x8 Bh, Bl;
      unpack8(q0, q1, Bh, Bl);
      acc = MFMA(Ah, Bh, acc);
      acc = MFMA(Al, Bh, acc);
      acc = MFMA(Ah, Bl, acc);
    }
    const int r0 = tr * 16 + h * 4;
#pragma unroll
    for (int j = 0; j < 4; ++j) {
      const int rr = r0 + j, cc = tc * 16 + lr;
      float v = acc[j];
      if (rr == cc) v += sr[rr];
      sS[rr * 36 + cc] = v;
    }
  }
  __syncthreads(); // B6

  // ---- p6: S^-1 in-register Gauss-Jordan on wave 0 (no pivoting, SPD>=I).
  if (w == 0) {
    const int mr = l >> 1, half = l & 1;
    float s0[16];
    const float *gbase = sS + mr * 36 + half * 16;
    {
      f4 v0 = *(const f4 *)(gbase + 0), v1 = *(const f4 *)(gbase + 4);
      f4 v2 = *(const f4 *)(gbase + 8), v3 = *(const f4 *)(gbase + 12);
#pragma unroll
      for (int j = 0; j < 4; ++j) {
        s0[j] = v0[j]; s0[4 + j] = v1[j]; s0[8 + j] = v2[j]; s0[12 + j] = v3[j];
      }
    }
#pragma unroll
    for (int p = 0; p < 32; ++p) {
      const int ph = p >> 4, pi = p & 15;
      float prow[16];
#pragma unroll
      for (int j = 0; j < 16; ++j) prow[j] = __shfl(s0[j], 2 * p + half, 64);
      const float dpp = __shfl(s0[pi], 2 * p + ph, 64);
      const float d = 1.0f / dpp;
      const float fv = __shfl(s0[pi], (l & 62) + ph, 64);
      if (mr == p) {
#pragma unroll
        for (int j = 0; j < 16; ++j) s0[j] = prow[j] * d;
        if (half == ph) s0[pi] = d;
      } else {
        const float fd = fv * d;
#pragma unroll
        for (int j = 0; j < 16; ++j) s0[j] = fmaf(-fd, prow[j], s0[j]);
        if (half == ph) s0[pi] = -fd;
      }
    }
    float *wbase = sS + mr * 36 + half * 16;
    f4 w0 = {s0[0], s0[1], s0[2], s0[3]};
    f4 w1 = {s0[4], s0[5], s0[6], s0[7]};
    f4 w2 = {s0[8], s0[9], s0[10], s0[11]};
    f4 w3 = {s0[12], s0[13], s0[14], s0[15]};
    *(f4 *)(wbase + 0) = w0;
    *(f4 *)(wbase + 4) = w1;
    *(f4 *)(wbase + 8) = w2;
    *(f4 *)(wbase + 12) = w3;
  }
  __syncthreads(); // B7

  // ---- p7 (MFMA): K = PHt * S^-1 (B row-read via S^-1 symmetry).
  //      Writes packed sK over dead T rows 32..63.
  {
    f32x4 acc[2] = {{0.f, 0.f, 0.f, 0.f}, {0.f, 0.f, 0.f, 0.f}};
    const int m = 16 * w + lr;
    const int xA = (m & 7) << 2;
    const int k = h * 8;
    u32x4 q0 = *(const u32x4 *)(sPHt + m * 32 + (k ^ xA));
    u32x4 q1 = *(const u32x4 *)(sPHt + m * 32 + ((k + 4) ^ xA));
    b16x8 Ah, Al;
    unpack8(q0, q1, Ah, Al);
#pragma unroll
    for (int t = 0; t < 2; ++t) {
      const int n = t * 16 + lr;
      f4 b0 = *(const f4 *)(sS + n * 36 + k);
      f4 b1 = *(const f4 *)(sS + n * 36 + k + 4);
      b16x8 Bh, Bl;
      split8v(b0, b1, Bh, Bl);
      acc[t] = MFMA(Ah, Bh, acc[t]);
      acc[t] = MFMA(Al, Bh, acc[t]);
      acc[t] = MFMA(Ah, Bl, acc[t]);
    }
    const int r0 = 16 * w + h * 4;
#pragma unroll
    for (int t = 0; t < 2; ++t)
#pragma unroll
      for (int j = 0; j < 4; ++j) {
        const int rr = r0 + j, cc = t * 16 + lr;
        sK[rr * 32 + (cc ^ ((rr & 7) << 2))] = packsplit(acc[t][j]);
      }
  }
  __syncthreads(); // B8

  // ---- p8: state_update (wave 0) + cov_update = cov_pred - K*PHt^T (MFMA)
  if (tid < 64) {
    float su = sy[tid];
    const int x = (tid & 7) << 2;
    const u32 *Kb = sK + tid * 32;
#pragma unroll
    for (int c0 = 0; c0 < 32; c0 += 4) {
      u32x4 q = *(const u32x4 *)(Kb + (c0 ^ x));
#pragma unroll
      for (int j = 0; j < 4; ++j)
        su = fmaf(unpackf(q[j]), sresid[c0 + j], su);
    }
    out[b * 64 + tid] = su;
  }
  {
    const int m = 16 * w + lr;
    const int xA = (m & 7) << 2;
    const int k = h * 8;
    u32x4 q0 = *(const u32x4 *)(sK + m * 32 + (k ^ xA));
    u32x4 q1 = *(const u32x4 *)(sK + m * 32 + ((k + 4) ^ xA));
#pragma unroll
    for (int j = 0; j < 4; ++j) { // negate both halves: -K
      q0[j] ^= 0x80008000u;
      q1[j] ^= 0x80008000u;
    }
    b16x8 Ah, Al;
    unpack8(q0, q1, Ah, Al);
    const int r0 = 16 * w + h * 4;
    float *outc = out + CU_OFF + (size_t)b * 4096;
#pragma unroll
    for (int t = 0; t < 4; ++t) {
      const int n = t * 16 + lr;
      const int xB = (n & 7) << 2;
      u32x4 p0 = *(const u32x4 *)(sPHt + n * 32 + (k ^ xB));
      u32x4 p1 = *(const u32x4 *)(sPHt + n * 32 + ((k + 4) ^ xB));
      b16x8 Bh, Bl;
      unpack8(p0, p1, Bh, Bl);
      f32x4 acc;
#pragma unroll
      for (int j = 0; j < 4; ++j) {
        const int rr = r0 + j;
        acc[j] = unpackf(sCov[rr * 64 + (n ^ ((rr & 7) << 2))]);
      }
      acc = MFMA(Ah, Bh, acc);
      acc = MFMA(Al, Bh, acc);
      acc = MFMA(Ah, Bl, acc);
#pragma unroll
      for (int j = 0; j < 4; ++j) {
        const int rr = r0 + j;
        outc[rr * 64 + n] = acc[j];
        if (rr == n) out[CD_OFF + b * 64 + rr] = acc[j];
      }
    }
  }
}

extern "C" void kernel_launch(void *const *d_in, const int *in_sizes, int n_in,
                              void *d_out, int out_size, void *d_ws,
                              size_t ws_size, hipStream_t stream) {
  const float *obs = (const float *)d_in[0];
  const float *prev_state = (const float *)d_in[1];
  const float *prev_cov = (const float *)d_in[2];
  const float *coeffs = (const float *)d_in[3];
  const float *Hm = (const float *)d_in[4];
  const float *logQ = (const float *)d_in[5];
  const float *logR = (const float *)d_in[6];
  const int *tptr = (const int *)d_in[7];
  (void)in_sizes; (void)n_in; (void)out_size; (void)d_ws; (void)ws_size;
  kalman_fused<<<dim3(4096), dim3(256), 0, stream>>>(
      obs, prev_state, prev_cov, coeffs, Hm, logQ, logR, tptr, (float *)d_out);
}